// Round 13
// baseline (455.080 us; speedup 1.0000x reference)
//
#include <hip/hip_runtime.h>

typedef __attribute__((ext_vector_type(8))) short bf16x8;
typedef __attribute__((ext_vector_type(4))) float f32x4;
typedef __attribute__((ext_vector_type(16))) float f32x16;
typedef __attribute__((address_space(1))) void gvoid_t;
typedef __attribute__((address_space(3))) void lvoid_t;

#define DEVI __device__ __forceinline__
#define SB __builtin_amdgcn_sched_barrier(0)

DEVI unsigned short f2bf(float f) {
    unsigned int u = __builtin_bit_cast(unsigned int, f);
    u += 0x7fffu + ((u >> 16) & 1u);   // RNE
    return (unsigned short)(u >> 16);
}

DEVI unsigned cvt_pk_bf16(float a, float b) {
    unsigned r;
    asm("v_cvt_pk_bf16_f32 %0, %1, %2" : "=v"(r) : "v"(a), "v"(b));
    return r;
}

DEVI f32x4 mfma16(bf16x8 a, bf16x8 b, f32x4 c) {
    return __builtin_amdgcn_mfma_f32_16x16x32_bf16(a, b, c, 0, 0, 0);
}

// ---------------- fp32 -> bf16 elementwise (8 elems/thread) ----------------
__global__ void k_convert(const float* __restrict__ in, unsigned short* __restrict__ out, int n8) {
    int i = blockIdx.x * 256 + threadIdx.x;
    if (i >= n8) return;
    const float4* p = (const float4*)in + (size_t)i * 2;
    float4 a = p[0], b = p[1];
    uint4 o;
    o.x = f2bf(a.x) | ((unsigned)f2bf(a.y) << 16);
    o.y = f2bf(a.z) | ((unsigned)f2bf(a.w) << 16);
    o.z = f2bf(b.x) | ((unsigned)f2bf(b.y) << 16);
    o.w = f2bf(b.z) | ((unsigned)f2bf(b.w) << 16);
    *((uint4*)out + i) = o;
}

// ---------------- transpose+convert: w[K][N] f32 -> wt[N][K] bf16 ----------------
__global__ void k_transpose(const float* __restrict__ w, unsigned short* __restrict__ wt, int K, int N) {
    __shared__ float tile[32][33];
    int n0 = blockIdx.x * 32, k0 = blockIdx.y * 32;
    int tx = threadIdx.x, ty = threadIdx.y;
#pragma unroll
    for (int r = 0; r < 32; r += 8)
        tile[ty + r][tx] = w[(size_t)(k0 + ty + r) * N + n0 + tx];
    __syncthreads();
#pragma unroll
    for (int r = 0; r < 32; r += 8)
        wt[(size_t)(n0 + ty + r) * K + k0 + tx] = f2bf(tile[tx][ty + r]);
}

// ---------------- V fragment-pack: vp[(bh*10+t)*4 + which*2+kc][lane][8] -----------
// value = V[bt,t*32+kc*16+hh*8+j][which*32+(l&31)]  (== old LDS-swizzled delivery)
__global__ __launch_bounds__(256) void k_vpack(const unsigned short* __restrict__ qkv,
                                               unsigned short* __restrict__ vp) {
    int bht = blockIdx.x;            // bh*10 + t
    int t = bht % 10, bh = bht / 10;
    int h = bh % 12, bt = bh / 12;
    int sub = threadIdx.x >> 6, l = threadIdx.x & 63;
    int q = l & 31, hh = l >> 5;
    int which = sub >> 1, kc = sub & 1;
    const unsigned short* base = qkv + (size_t)(bt * 320 + t * 32 + kc * 16 + hh * 8) * 2304
                                 + 1536 + h * 64 + which * 32 + q;
    union { uint4 u; unsigned short s[8]; } o;
#pragma unroll
    for (int j = 0; j < 8; ++j)
        o.s[j] = base[(size_t)j * 2304];
    *(uint4*)(vp + ((size_t)bht * 4 + sub) * 512 + l * 8) = o.u;
}

// ---------------- 256x256 free-run bf16 GEMM: all t+1 stages in P0 (round-8) --------
template <bool OUT_BF16>
__global__ __launch_bounds__(512, 2) void k_gemm256(const unsigned short* __restrict__ A,
                                                    const unsigned short* __restrict__ Bt,
                                                    const float* __restrict__ bias,
                                                    void* __restrict__ out,
                                                    int M, int N, int K) {
    __shared__ unsigned short smem[65536];   // A[2][256][64] @0, B[2][256][64] @32768

    const int tid = threadIdx.x;
    const int nwg = gridDim.x, bid = blockIdx.x;
    const int q8 = nwg >> 3, r8 = nwg & 7;
    const int xcd = bid & 7, lid = bid >> 3;
    const int swz = ((xcd < r8) ? xcd * (q8 + 1) : r8 * (q8 + 1) + (xcd - r8) * q8) + lid;
    const int ntn = N >> 8;
    const int bm = swz / ntn, bn = swz % ntn;

    const int lane = tid & 63, wid = tid >> 6;
    const int wr = wid >> 2, wc = wid & 3;
    const int lr = lane & 15, lg = lane >> 4;
    const int cswz = (lr & 7) << 3;
    const int col0 = (lg * 8) ^ cswz;

    const int NT = K >> 6;

    const int srowl = tid >> 3;
    const int scole = ((tid & 7) ^ (srowl & 7)) << 3;
    const unsigned short* aSrc = A  + (size_t)(bm * 256 + srowl) * K + scole;
    const unsigned short* bSrc = Bt + (size_t)(bn * 256 + srowl) * K + scole;

#define STG(matOff, srcBase, qq, koff, bufw)                                              \
    __builtin_amdgcn_global_load_lds((gvoid_t*)((srcBase) + (size_t)(qq) * 64 * K + (koff)), \
        (lvoid_t*)(smem + (matOff) + (bufw) * 16384 + (qq) * 4096 + tid * 8), 16, 0, 0)
#define LDA(mf, base, rowoff, kk) \
    *(const bf16x8*)((base) + ((rowoff) + (mf) * 16 + lr) * 64 + (col0 ^ ((kk) * 32)))

    f32x4 acc[8][4];
#pragma unroll
    for (int i = 0; i < 8; ++i)
#pragma unroll
        for (int j = 0; j < 4; ++j) acc[i][j] = (f32x4){0.f, 0.f, 0.f, 0.f};

    {   // prologue: tile0 fully + tile1 A0,A2
        const int k1 = (NT > 1) ? 64 : 0;
        STG(0, aSrc, 0, 0, 0); STG(0, aSrc, 1, 0, 0); STG(0, aSrc, 2, 0, 0); STG(0, aSrc, 3, 0, 0);
        STG(32768, bSrc, 0, 0, 0); STG(32768, bSrc, 1, 0, 0); STG(32768, bSrc, 2, 0, 0); STG(32768, bSrc, 3, 0, 0);
        STG(0, aSrc, 0, k1, 1); STG(0, aSrc, 2, k1, 1);
        asm volatile("s_waitcnt vmcnt(2)" ::: "memory");
        __builtin_amdgcn_s_barrier();
    }

#pragma unroll 1
    for (int t = 0; t < NT; ++t) {
        const int bufR = t & 1, bufW = bufR ^ 1;
        const int ko1 = (t + 1 < NT) ? (t + 1) * 64 : 0;
        const int ko2 = (t + 2 < NT) ? (t + 2) * 64 : 0;
        const unsigned short* abuf = smem + bufR * 16384;
        const unsigned short* bbuf = smem + 32768 + bufR * 16384;
        bf16x8 afv[4][2], b01[2][2], b23[2][2];

        // ===== P0: (mh=0) x (nh=0); issue ALL 6 t+1 stages here =====
#pragma unroll
        for (int j = 0; j < 2; ++j)
#pragma unroll
            for (int kk = 0; kk < 2; ++kk)
                b01[j][kk] = LDA(j, bbuf, wc * 64, kk);
#pragma unroll
        for (int mf = 0; mf < 2; ++mf)
#pragma unroll
            for (int kk = 0; kk < 2; ++kk)
                afv[mf][kk] = LDA(mf, abuf, wr * 128, kk);
        SB;
#pragma unroll
        for (int mf = 2; mf < 4; ++mf)
#pragma unroll
            for (int kk = 0; kk < 2; ++kk)
                afv[mf][kk] = LDA(mf, abuf, wr * 128, kk);
        SB;
        STG(32768, bSrc, 0, ko1, bufW); STG(32768, bSrc, 1, ko1, bufW);
        STG(32768, bSrc, 2, ko1, bufW); STG(32768, bSrc, 3, ko1, bufW);
        STG(0, aSrc, 1, ko1, bufW); STG(0, aSrc, 3, ko1, bufW);
        asm volatile("s_waitcnt lgkmcnt(4)" ::: "memory"); SB;
        __builtin_amdgcn_s_setprio(1);
#pragma unroll
        for (int mf = 0; mf < 2; ++mf)
#pragma unroll
            for (int j = 0; j < 2; ++j)
#pragma unroll
                for (int kk = 0; kk < 2; ++kk)
                    acc[mf][j] = mfma16(afv[mf][kk], b01[j][kk], acc[mf][j]);
        __builtin_amdgcn_s_setprio(0);
        asm volatile("s_waitcnt lgkmcnt(0)" ::: "memory"); SB;
        __builtin_amdgcn_s_setprio(1);
#pragma unroll
        for (int mf = 2; mf < 4; ++mf)
#pragma unroll
            for (int j = 0; j < 2; ++j)
#pragma unroll
                for (int kk = 0; kk < 2; ++kk)
                    acc[mf][j] = mfma16(afv[mf][kk], b01[j][kk], acc[mf][j]);
        __builtin_amdgcn_s_setprio(0);

        // ===== P1: (mh=0) x (nh=1) =====
#pragma unroll
        for (int kk = 0; kk < 2; ++kk)
            b23[0][kk] = LDA(2, bbuf, wc * 64, kk);
        SB;
#pragma unroll
        for (int kk = 0; kk < 2; ++kk)
            b23[1][kk] = LDA(3, bbuf, wc * 64, kk);
        SB;
        asm volatile("s_waitcnt lgkmcnt(2)" ::: "memory"); SB;
        __builtin_amdgcn_s_setprio(1);
#pragma unroll
        for (int mf = 0; mf < 4; ++mf)
#pragma unroll
            for (int kk = 0; kk < 2; ++kk)
                acc[mf][2] = mfma16(afv[mf][kk], b23[0][kk], acc[mf][2]);
        __builtin_amdgcn_s_setprio(0);
        asm volatile("s_waitcnt lgkmcnt(0)" ::: "memory"); SB;
        __builtin_amdgcn_s_setprio(1);
#pragma unroll
        for (int mf = 0; mf < 4; ++mf)
#pragma unroll
            for (int kk = 0; kk < 2; ++kk)
                acc[mf][3] = mfma16(afv[mf][kk], b23[1][kk], acc[mf][3]);
        __builtin_amdgcn_s_setprio(0);

        // ===== P2: (mh=1) x (nh=1) =====
#pragma unroll
        for (int mf = 0; mf < 2; ++mf)
#pragma unroll
            for (int kk = 0; kk < 2; ++kk)
                afv[mf][kk] = LDA(mf, abuf, wr * 128 + 64, kk);
        SB;
#pragma unroll
        for (int mf = 2; mf < 4; ++mf)
#pragma unroll
            for (int kk = 0; kk < 2; ++kk)
                afv[mf][kk] = LDA(mf, abuf, wr * 128 + 64, kk);
        SB;
        asm volatile("s_waitcnt lgkmcnt(4)" ::: "memory"); SB;
        __builtin_amdgcn_s_setprio(1);
#pragma unroll
        for (int mf = 0; mf < 2; ++mf)
#pragma unroll
            for (int j = 0; j < 2; ++j)
#pragma unroll
                for (int kk = 0; kk < 2; ++kk)
                    acc[4 + mf][2 + j] = mfma16(afv[mf][kk], b23[j][kk], acc[4 + mf][2 + j]);
        __builtin_amdgcn_s_setprio(0);
        asm volatile("s_waitcnt lgkmcnt(0)" ::: "memory"); SB;
        __builtin_amdgcn_s_setprio(1);
#pragma unroll
        for (int mf = 2; mf < 4; ++mf)
#pragma unroll
            for (int j = 0; j < 2; ++j)
#pragma unroll
                for (int kk = 0; kk < 2; ++kk)
                    acc[4 + mf][2 + j] = mfma16(afv[mf][kk], b23[j][kk], acc[4 + mf][2 + j]);
        __builtin_amdgcn_s_setprio(0);

        // ===== P3: (mh=1) x (nh=0) — regs only =====
        __builtin_amdgcn_s_setprio(1);
#pragma unroll
        for (int mf = 0; mf < 4; ++mf)
#pragma unroll
            for (int j = 0; j < 2; ++j)
#pragma unroll
                for (int kk = 0; kk < 2; ++kk)
                    acc[4 + mf][j] = mfma16(afv[mf][kk], b01[j][kk], acc[4 + mf][j]);
        __builtin_amdgcn_s_setprio(0);
        asm volatile("s_waitcnt vmcnt(0)" ::: "memory");
        __builtin_amdgcn_s_barrier();
        STG(0, aSrc, 0, ko2, bufR); STG(0, aSrc, 2, ko2, bufR);
    }
#undef STG
#undef LDA

    // ---- epilogue: drain stray prefetches, block-sync, then LDS-staged stores ----
    asm volatile("s_waitcnt vmcnt(0)" ::: "memory");
    __syncthreads();
    float bv[4];
#pragma unroll
    for (int nf = 0; nf < 4; ++nf)
        bv[nf] = bias[bn * 256 + wc * 64 + nf * 16 + lr];

    if (OUT_BF16) {
        unsigned short* ebuf = smem + wid * 8192;
#pragma unroll
        for (int h = 0; h < 2; ++h) {
#pragma unroll
            for (int mf4 = 0; mf4 < 4; ++mf4) {
                int mf = h * 4 + mf4;
#pragma unroll
                for (int nf = 0; nf < 4; ++nf)
#pragma unroll
                    for (int i = 0; i < 4; ++i)
                        ebuf[(mf4 * 16 + lg * 4 + i) * 72 + nf * 16 + lr] = f2bf(acc[mf][nf][i] + bv[nf]);
            }
            asm volatile("s_waitcnt lgkmcnt(0)" ::: "memory"); SB;
#pragma unroll
            for (int ps = 0; ps < 8; ++ps) {
                int rl = ps * 8 + (lane >> 3), ck = lane & 7;
                uint4 vv = *(const uint4*)&ebuf[rl * 72 + ck * 8];
                int grow = bm * 256 + wr * 128 + h * 64 + rl;
                int gcol = bn * 256 + wc * 64 + ck * 8;
                *(uint4*)&((unsigned short*)out)[(size_t)grow * N + gcol] = vv;
            }
            asm volatile("s_waitcnt lgkmcnt(0)" ::: "memory"); SB;
        }
    } else {
        float* ebuf = (float*)smem + wid * 4096;
#pragma unroll
        for (int qq = 0; qq < 4; ++qq) {
#pragma unroll
            for (int m2 = 0; m2 < 2; ++m2) {
                int mf = qq * 2 + m2;
#pragma unroll
                for (int nf = 0; nf < 4; ++nf)
#pragma unroll
                    for (int i = 0; i < 4; ++i)
                        ebuf[(m2 * 16 + lg * 4 + i) * 68 + nf * 16 + lr] = acc[mf][nf][i] + bv[nf];
            }
            asm volatile("s_waitcnt lgkmcnt(0)" ::: "memory"); SB;
#pragma unroll
            for (int ps = 0; ps < 8; ++ps) {
                int rl = ps * 4 + (lane >> 4), ck = lane & 15;
                uint4 vv = *(const uint4*)&ebuf[rl * 68 + ck * 4];
                int grow = bm * 256 + wr * 128 + qq * 32 + rl;
                int gcol = bn * 256 + wc * 64 + ck * 4;
                *(uint4*)&((float*)out)[(size_t)grow * N + gcol] = vv;
            }
            asm volatile("s_waitcnt lgkmcnt(0)" ::: "memory"); SB;
        }
    }
}

// ---------------- fused flash attention v7: 1 wave/block, zero LDS, zero barriers ---
// Block = (bh, w): wave owns q-tile w of head bh. K direct from qkv; V packed (vp).
__global__ __launch_bounds__(64) void k_attn7(const unsigned short* __restrict__ qkv,
                                              const unsigned short* __restrict__ vp,
                                              unsigned short* __restrict__ y) {
    int blk = blockIdx.x;
    int w = blk % 10, bh = blk / 10;
    int bt = bh / 12, h = bh % 12;
    const unsigned short* Qg = qkv + (size_t)bt * 320 * 2304 + h * 64;
    const unsigned short* Kg = Qg + 768;
    const unsigned short* Vpb = vp + (size_t)bh * 20480;   // 10 t * 4 frag * 512

    int l = threadIdx.x;
    int q = l & 31, hh = l >> 5;
    int q0 = w * 32;
    int ntile = (w < 2) ? 2 : 10;

    bf16x8 qf[4];
#pragma unroll
    for (int c = 0; c < 4; ++c)
        qf[c] = *(const bf16x8*)(Qg + (size_t)(q0 + q) * 2304 + c * 16 + hh * 8);

    f32x16 o0 = (f32x16)0.f, o1 = (f32x16)0.f;
    float m = -3e38f, lsum = 0.f;
    const float SC = 0.125f * 1.44269504089f;

    for (int t = 0; t < ntile; ++t) {
        bf16x8 kf[4];
#pragma unroll
        for (int c = 0; c < 4; ++c)
            kf[c] = *(const bf16x8*)(Kg + (size_t)(t * 32 + q) * 2304 + c * 16 + hh * 8);
        // V fragments (packed, coalesced; independent of kf -> overlaps QK)
        bf16x8 v00 = *(const bf16x8*)(Vpb + (t * 4 + 0) * 512 + l * 8);
        bf16x8 v01 = *(const bf16x8*)(Vpb + (t * 4 + 1) * 512 + l * 8);
        bf16x8 v10 = *(const bf16x8*)(Vpb + (t * 4 + 2) * 512 + l * 8);
        bf16x8 v11 = *(const bf16x8*)(Vpb + (t * 4 + 3) * 512 + l * 8);

        f32x16 sacc = (f32x16)0.f;
#pragma unroll
        for (int c = 0; c < 4; ++c)
            sacc = __builtin_amdgcn_mfma_f32_32x32x16_bf16(kf[c], qf[c], sacc, 0, 0, 0);

        float p[16];
#pragma unroll
        for (int r = 0; r < 16; ++r) p[r] = sacc[r] * SC;
        float tm = fmaxf(
            fmaxf(fmaxf(fmaxf(p[0], p[1]), fmaxf(p[2], p[3])),
                  fmaxf(fmaxf(p[4], p[5]), fmaxf(p[6], p[7]))),
            fmaxf(fmaxf(fmaxf(p[8], p[9]), fmaxf(p[10], p[11])),
                  fmaxf(fmaxf(p[12], p[13]), fmaxf(p[14], p[15]))));
        tm = fmaxf(tm, __shfl_xor(tm, 32));
        if (!__all(tm <= m + 8.f)) {
            float mn = fmaxf(m, tm);
            float al = __builtin_amdgcn_exp2f(m - mn);
            lsum *= al;
#pragma unroll
            for (int r = 0; r < 16; ++r) { o0[r] *= al; o1[r] *= al; }
            m = mn;
        }
#pragma unroll
        for (int r = 0; r < 16; ++r) p[r] = __builtin_amdgcn_exp2f(p[r] - m);
        float rs =
            ((p[0] + p[1]) + (p[2] + p[3])) + ((p[4] + p[5]) + (p[6] + p[7])) +
            (((p[8] + p[9]) + (p[10] + p[11])) + ((p[12] + p[13]) + (p[14] + p[15])));
        lsum += rs;

        unsigned a0 = cvt_pk_bf16(p[0], p[1]);
        unsigned a1 = cvt_pk_bf16(p[2], p[3]);
        unsigned b0 = cvt_pk_bf16(p[4], p[5]);
        unsigned b1 = cvt_pk_bf16(p[6], p[7]);
        asm("v_permlane32_swap_b32 %0, %1" : "+v"(a0), "+v"(b0));
        asm("v_permlane32_swap_b32 %0, %1" : "+v"(a1), "+v"(b1));
        unsigned c0 = cvt_pk_bf16(p[8], p[9]);
        unsigned c1 = cvt_pk_bf16(p[10], p[11]);
        unsigned d0 = cvt_pk_bf16(p[12], p[13]);
        unsigned d1 = cvt_pk_bf16(p[14], p[15]);
        asm("v_permlane32_swap_b32 %0, %1" : "+v"(c0), "+v"(d0));
        asm("v_permlane32_swap_b32 %0, %1" : "+v"(c1), "+v"(d1));
        union { unsigned u[4]; bf16x8 v; } pf0, pf1;
        pf0.u[0] = a0; pf0.u[1] = a1; pf0.u[2] = b0; pf0.u[3] = b1;
        pf1.u[0] = c0; pf1.u[1] = c1; pf1.u[2] = d0; pf1.u[3] = d1;

        o0 = __builtin_amdgcn_mfma_f32_32x32x16_bf16(v00, pf0.v, o0, 0, 0, 0);
        o0 = __builtin_amdgcn_mfma_f32_32x32x16_bf16(v01, pf1.v, o0, 0, 0, 0);
        o1 = __builtin_amdgcn_mfma_f32_32x32x16_bf16(v10, pf0.v, o1, 0, 0, 0);
        o1 = __builtin_amdgcn_mfma_f32_32x32x16_bf16(v11, pf1.v, o1, 0, 0, 0);
    }

    lsum += __shfl_xor(lsum, 32);
    float inv = 1.f / lsum;
    unsigned short* yp = y + (size_t)(bt * 320 + q0 + q) * 768 + h * 64;
#pragma unroll
    for (int r = 0; r < 16; r += 2) {
        int dr = (r & 3) + 8 * (r >> 2) + 4 * hh;
        *(unsigned*)(yp + dr) =
            (unsigned)f2bf(o0[r] * inv) | ((unsigned)f2bf(o0[r + 1] * inv) << 16);
        *(unsigned*)(yp + 32 + dr) =
            (unsigned)f2bf(o1[r] * inv) | ((unsigned)f2bf(o1[r + 1] * inv) << 16);
    }
}

// ---------------- launcher ----------------
extern "C" void kernel_launch(void* const* d_in, const int* in_sizes, int n_in,
                              void* d_out, int out_size, void* d_ws, size_t ws_size,
                              hipStream_t stream) {
    const float* x     = (const float*)d_in[0];
    const float* qkv_w = (const float*)d_in[1];
    const float* qkv_b = (const float*)d_in[2];
    const float* out_w = (const float*)d_in[3];
    const float* out_b = (const float*)d_in[4];

    const int M = 40960;  // B*T*S = 4*32*320
    unsigned short* xb  = (unsigned short*)d_ws;
    unsigned short* w1t = xb + (size_t)M * 768;           // [2304][768]
    unsigned short* w2t = w1t + (size_t)2304 * 768;       // [768][768]
    unsigned short* qkv = w2t + (size_t)768 * 768;        // [M][2304]
    unsigned short* yb  = qkv + (size_t)M * 2304;         // [M][768]
    unsigned short* vp  = xb;                             // aliases xb (dead after gemm1): 62.9MB

    k_convert<<<(M * 768 / 8 + 255) / 256, 256, 0, stream>>>(x, xb, M * 768 / 8);
    k_transpose<<<dim3(2304 / 32, 768 / 32), dim3(32, 8), 0, stream>>>(qkv_w, w1t, 768, 2304);
    k_transpose<<<dim3(768 / 32, 768 / 32), dim3(32, 8), 0, stream>>>(out_w, w2t, 768, 768);

    k_gemm256<true><<<(M / 256) * (2304 / 256), 512, 0, stream>>>(xb, w1t, qkv_b, (void*)qkv, M, 2304, 768);
    k_vpack<<<1536 * 10, 256, 0, stream>>>(qkv, vp);
    k_attn7<<<1536 * 10, 64, 0, stream>>>(qkv, vp, yb);
    k_gemm256<false><<<(M / 256) * (768 / 256), 512, 0, stream>>>(yb, w2t, out_b, d_out, M, 768, 768);
}

// Round 14
// 410.036 us; speedup vs baseline: 1.1099x; 1.1099x over previous
//
#include <hip/hip_runtime.h>

typedef __attribute__((ext_vector_type(8))) short bf16x8;
typedef __attribute__((ext_vector_type(4))) float f32x4;
typedef __attribute__((ext_vector_type(16))) float f32x16;
typedef __attribute__((address_space(1))) void gvoid_t;
typedef __attribute__((address_space(3))) void lvoid_t;

#define DEVI __device__ __forceinline__
#define SB __builtin_amdgcn_sched_barrier(0)

DEVI unsigned short f2bf(float f) {
    unsigned int u = __builtin_bit_cast(unsigned int, f);
    u += 0x7fffu + ((u >> 16) & 1u);   // RNE
    return (unsigned short)(u >> 16);
}

DEVI unsigned cvt_pk_bf16(float a, float b) {
    unsigned r;
    asm("v_cvt_pk_bf16_f32 %0, %1, %2" : "=v"(r) : "v"(a), "v"(b));
    return r;
}

DEVI f32x4 mfma16(bf16x8 a, bf16x8 b, f32x4 c) {
    return __builtin_amdgcn_mfma_f32_16x16x32_bf16(a, b, c, 0, 0, 0);
}

// ---------------- fp32 -> bf16 elementwise (8 elems/thread) ----------------
__global__ void k_convert(const float* __restrict__ in, unsigned short* __restrict__ out, int n8) {
    int i = blockIdx.x * 256 + threadIdx.x;
    if (i >= n8) return;
    const float4* p = (const float4*)in + (size_t)i * 2;
    float4 a = p[0], b = p[1];
    uint4 o;
    o.x = f2bf(a.x) | ((unsigned)f2bf(a.y) << 16);
    o.y = f2bf(a.z) | ((unsigned)f2bf(a.w) << 16);
    o.z = f2bf(b.x) | ((unsigned)f2bf(b.y) << 16);
    o.w = f2bf(b.z) | ((unsigned)f2bf(b.w) << 16);
    *((uint4*)out + i) = o;
}

// ---------------- transpose+convert: w[K][N] f32 -> wt[N][K] bf16 ----------------
__global__ void k_transpose(const float* __restrict__ w, unsigned short* __restrict__ wt, int K, int N) {
    __shared__ float tile[32][33];
    int n0 = blockIdx.x * 32, k0 = blockIdx.y * 32;
    int tx = threadIdx.x, ty = threadIdx.y;
#pragma unroll
    for (int r = 0; r < 32; r += 8)
        tile[ty + r][tx] = w[(size_t)(k0 + ty + r) * N + n0 + tx];
    __syncthreads();
#pragma unroll
    for (int r = 0; r < 32; r += 8)
        wt[(size_t)(n0 + ty + r) * K + k0 + tx] = f2bf(tile[tx][ty + r]);
}

// ---------------- V fragment-pack: vp[(bh*10+t)*4 + which*2+kc][lane][8] -----------
__global__ __launch_bounds__(256) void k_vpack(const unsigned short* __restrict__ qkv,
                                               unsigned short* __restrict__ vp) {
    int bht = blockIdx.x;            // bh*10 + t
    int t = bht % 10, bh = bht / 10;
    int h = bh % 12, bt = bh / 12;
    int sub = threadIdx.x >> 6, l = threadIdx.x & 63;
    int q = l & 31, hh = l >> 5;
    int which = sub >> 1, kc = sub & 1;
    const unsigned short* base = qkv + (size_t)(bt * 320 + t * 32 + kc * 16 + hh * 8) * 2304
                                 + 1536 + h * 64 + which * 32 + q;
    union { uint4 u; unsigned short s[8]; } o;
#pragma unroll
    for (int j = 0; j < 8; ++j)
        o.s[j] = base[(size_t)j * 2304];
    *(uint4*)(vp + ((size_t)bht * 4 + sub) * 512 + l * 8) = o.u;
}

// ---------------- 256x256 free-run bf16 GEMM: all t+1 stages in P0 (round-8) --------
template <bool OUT_BF16>
__global__ __launch_bounds__(512, 2) void k_gemm256(const unsigned short* __restrict__ A,
                                                    const unsigned short* __restrict__ Bt,
                                                    const float* __restrict__ bias,
                                                    void* __restrict__ out,
                                                    int M, int N, int K) {
    __shared__ unsigned short smem[65536];   // A[2][256][64] @0, B[2][256][64] @32768

    const int tid = threadIdx.x;
    const int nwg = gridDim.x, bid = blockIdx.x;
    const int q8 = nwg >> 3, r8 = nwg & 7;
    const int xcd = bid & 7, lid = bid >> 3;
    const int swz = ((xcd < r8) ? xcd * (q8 + 1) : r8 * (q8 + 1) + (xcd - r8) * q8) + lid;
    const int ntn = N >> 8;
    const int bm = swz / ntn, bn = swz % ntn;

    const int lane = tid & 63, wid = tid >> 6;
    const int wr = wid >> 2, wc = wid & 3;
    const int lr = lane & 15, lg = lane >> 4;
    const int cswz = (lr & 7) << 3;
    const int col0 = (lg * 8) ^ cswz;

    const int NT = K >> 6;

    const int srowl = tid >> 3;
    const int scole = ((tid & 7) ^ (srowl & 7)) << 3;
    const unsigned short* aSrc = A  + (size_t)(bm * 256 + srowl) * K + scole;
    const unsigned short* bSrc = Bt + (size_t)(bn * 256 + srowl) * K + scole;

#define STG(matOff, srcBase, qq, koff, bufw)                                              \
    __builtin_amdgcn_global_load_lds((gvoid_t*)((srcBase) + (size_t)(qq) * 64 * K + (koff)), \
        (lvoid_t*)(smem + (matOff) + (bufw) * 16384 + (qq) * 4096 + tid * 8), 16, 0, 0)
#define LDA(mf, base, rowoff, kk) \
    *(const bf16x8*)((base) + ((rowoff) + (mf) * 16 + lr) * 64 + (col0 ^ ((kk) * 32)))

    f32x4 acc[8][4];
#pragma unroll
    for (int i = 0; i < 8; ++i)
#pragma unroll
        for (int j = 0; j < 4; ++j) acc[i][j] = (f32x4){0.f, 0.f, 0.f, 0.f};

    {   // prologue: tile0 fully + tile1 A0,A2
        const int k1 = (NT > 1) ? 64 : 0;
        STG(0, aSrc, 0, 0, 0); STG(0, aSrc, 1, 0, 0); STG(0, aSrc, 2, 0, 0); STG(0, aSrc, 3, 0, 0);
        STG(32768, bSrc, 0, 0, 0); STG(32768, bSrc, 1, 0, 0); STG(32768, bSrc, 2, 0, 0); STG(32768, bSrc, 3, 0, 0);
        STG(0, aSrc, 0, k1, 1); STG(0, aSrc, 2, k1, 1);
        asm volatile("s_waitcnt vmcnt(2)" ::: "memory");
        __builtin_amdgcn_s_barrier();
    }

#pragma unroll 1
    for (int t = 0; t < NT; ++t) {
        const int bufR = t & 1, bufW = bufR ^ 1;
        const int ko1 = (t + 1 < NT) ? (t + 1) * 64 : 0;
        const int ko2 = (t + 2 < NT) ? (t + 2) * 64 : 0;
        const unsigned short* abuf = smem + bufR * 16384;
        const unsigned short* bbuf = smem + 32768 + bufR * 16384;
        bf16x8 afv[4][2], b01[2][2], b23[2][2];

        // ===== P0: (mh=0) x (nh=0); issue ALL 6 t+1 stages here =====
#pragma unroll
        for (int j = 0; j < 2; ++j)
#pragma unroll
            for (int kk = 0; kk < 2; ++kk)
                b01[j][kk] = LDA(j, bbuf, wc * 64, kk);
#pragma unroll
        for (int mf = 0; mf < 2; ++mf)
#pragma unroll
            for (int kk = 0; kk < 2; ++kk)
                afv[mf][kk] = LDA(mf, abuf, wr * 128, kk);
        SB;
#pragma unroll
        for (int mf = 2; mf < 4; ++mf)
#pragma unroll
            for (int kk = 0; kk < 2; ++kk)
                afv[mf][kk] = LDA(mf, abuf, wr * 128, kk);
        SB;
        STG(32768, bSrc, 0, ko1, bufW); STG(32768, bSrc, 1, ko1, bufW);
        STG(32768, bSrc, 2, ko1, bufW); STG(32768, bSrc, 3, ko1, bufW);
        STG(0, aSrc, 1, ko1, bufW); STG(0, aSrc, 3, ko1, bufW);
        asm volatile("s_waitcnt lgkmcnt(4)" ::: "memory"); SB;
        __builtin_amdgcn_s_setprio(1);
#pragma unroll
        for (int mf = 0; mf < 2; ++mf)
#pragma unroll
            for (int j = 0; j < 2; ++j)
#pragma unroll
                for (int kk = 0; kk < 2; ++kk)
                    acc[mf][j] = mfma16(afv[mf][kk], b01[j][kk], acc[mf][j]);
        __builtin_amdgcn_s_setprio(0);
        asm volatile("s_waitcnt lgkmcnt(0)" ::: "memory"); SB;
        __builtin_amdgcn_s_setprio(1);
#pragma unroll
        for (int mf = 2; mf < 4; ++mf)
#pragma unroll
            for (int j = 0; j < 2; ++j)
#pragma unroll
                for (int kk = 0; kk < 2; ++kk)
                    acc[mf][j] = mfma16(afv[mf][kk], b01[j][kk], acc[mf][j]);
        __builtin_amdgcn_s_setprio(0);

        // ===== P1: (mh=0) x (nh=1) =====
#pragma unroll
        for (int kk = 0; kk < 2; ++kk)
            b23[0][kk] = LDA(2, bbuf, wc * 64, kk);
        SB;
#pragma unroll
        for (int kk = 0; kk < 2; ++kk)
            b23[1][kk] = LDA(3, bbuf, wc * 64, kk);
        SB;
        asm volatile("s_waitcnt lgkmcnt(2)" ::: "memory"); SB;
        __builtin_amdgcn_s_setprio(1);
#pragma unroll
        for (int mf = 0; mf < 4; ++mf)
#pragma unroll
            for (int kk = 0; kk < 2; ++kk)
                acc[mf][2] = mfma16(afv[mf][kk], b23[0][kk], acc[mf][2]);
        __builtin_amdgcn_s_setprio(0);
        asm volatile("s_waitcnt lgkmcnt(0)" ::: "memory"); SB;
        __builtin_amdgcn_s_setprio(1);
#pragma unroll
        for (int mf = 0; mf < 4; ++mf)
#pragma unroll
            for (int kk = 0; kk < 2; ++kk)
                acc[mf][3] = mfma16(afv[mf][kk], b23[1][kk], acc[mf][3]);
        __builtin_amdgcn_s_setprio(0);

        // ===== P2: (mh=1) x (nh=1) =====
#pragma unroll
        for (int mf = 0; mf < 2; ++mf)
#pragma unroll
            for (int kk = 0; kk < 2; ++kk)
                afv[mf][kk] = LDA(mf, abuf, wr * 128 + 64, kk);
        SB;
#pragma unroll
        for (int mf = 2; mf < 4; ++mf)
#pragma unroll
            for (int kk = 0; kk < 2; ++kk)
                afv[mf][kk] = LDA(mf, abuf, wr * 128 + 64, kk);
        SB;
        asm volatile("s_waitcnt lgkmcnt(4)" ::: "memory"); SB;
        __builtin_amdgcn_s_setprio(1);
#pragma unroll
        for (int mf = 0; mf < 2; ++mf)
#pragma unroll
            for (int j = 0; j < 2; ++j)
#pragma unroll
                for (int kk = 0; kk < 2; ++kk)
                    acc[4 + mf][2 + j] = mfma16(afv[mf][kk], b23[j][kk], acc[4 + mf][2 + j]);
        __builtin_amdgcn_s_setprio(0);
        asm volatile("s_waitcnt lgkmcnt(0)" ::: "memory"); SB;
        __builtin_amdgcn_s_setprio(1);
#pragma unroll
        for (int mf = 2; mf < 4; ++mf)
#pragma unroll
            for (int j = 0; j < 2; ++j)
#pragma unroll
                for (int kk = 0; kk < 2; ++kk)
                    acc[4 + mf][2 + j] = mfma16(afv[mf][kk], b23[j][kk], acc[4 + mf][2 + j]);
        __builtin_amdgcn_s_setprio(0);

        // ===== P3: (mh=1) x (nh=0) — regs only =====
        __builtin_amdgcn_s_setprio(1);
#pragma unroll
        for (int mf = 0; mf < 4; ++mf)
#pragma unroll
            for (int j = 0; j < 2; ++j)
#pragma unroll
                for (int kk = 0; kk < 2; ++kk)
                    acc[4 + mf][j] = mfma16(afv[mf][kk], b01[j][kk], acc[4 + mf][j]);
        __builtin_amdgcn_s_setprio(0);
        asm volatile("s_waitcnt vmcnt(0)" ::: "memory");
        __builtin_amdgcn_s_barrier();
        STG(0, aSrc, 0, ko2, bufR); STG(0, aSrc, 2, ko2, bufR);
    }
#undef STG
#undef LDA

    // ---- epilogue: drain stray prefetches, block-sync, then LDS-staged stores ----
    asm volatile("s_waitcnt vmcnt(0)" ::: "memory");
    __syncthreads();
    float bv[4];
#pragma unroll
    for (int nf = 0; nf < 4; ++nf)
        bv[nf] = bias[bn * 256 + wc * 64 + nf * 16 + lr];

    if (OUT_BF16) {
        unsigned short* ebuf = smem + wid * 8192;
#pragma unroll
        for (int h = 0; h < 2; ++h) {
#pragma unroll
            for (int mf4 = 0; mf4 < 4; ++mf4) {
                int mf = h * 4 + mf4;
#pragma unroll
                for (int nf = 0; nf < 4; ++nf)
#pragma unroll
                    for (int i = 0; i < 4; ++i)
                        ebuf[(mf4 * 16 + lg * 4 + i) * 72 + nf * 16 + lr] = f2bf(acc[mf][nf][i] + bv[nf]);
            }
            asm volatile("s_waitcnt lgkmcnt(0)" ::: "memory"); SB;
#pragma unroll
            for (int ps = 0; ps < 8; ++ps) {
                int rl = ps * 8 + (lane >> 3), ck = lane & 7;
                uint4 vv = *(const uint4*)&ebuf[rl * 72 + ck * 8];
                int grow = bm * 256 + wr * 128 + h * 64 + rl;
                int gcol = bn * 256 + wc * 64 + ck * 8;
                *(uint4*)&((unsigned short*)out)[(size_t)grow * N + gcol] = vv;
            }
            asm volatile("s_waitcnt lgkmcnt(0)" ::: "memory"); SB;
        }
    } else {
        float* ebuf = (float*)smem + wid * 4096;
#pragma unroll
        for (int qq = 0; qq < 4; ++qq) {
#pragma unroll
            for (int m2 = 0; m2 < 2; ++m2) {
                int mf = qq * 2 + m2;
#pragma unroll
                for (int nf = 0; nf < 4; ++nf)
#pragma unroll
                    for (int i = 0; i < 4; ++i)
                        ebuf[(m2 * 16 + lg * 4 + i) * 68 + nf * 16 + lr] = acc[mf][nf][i] + bv[nf];
            }
            asm volatile("s_waitcnt lgkmcnt(0)" ::: "memory"); SB;
#pragma unroll
            for (int ps = 0; ps < 8; ++ps) {
                int rl = ps * 4 + (lane >> 4), ck = lane & 15;
                uint4 vv = *(const uint4*)&ebuf[rl * 68 + ck * 4];
                int grow = bm * 256 + wr * 128 + qq * 32 + rl;
                int gcol = bn * 256 + wc * 64 + ck * 4;
                *(uint4*)&((float*)out)[(size_t)grow * N + gcol] = vv;
            }
            asm volatile("s_waitcnt lgkmcnt(0)" ::: "memory"); SB;
        }
    }
}

// ---------------- fused flash attention v8: 12 waves/block, zero LDS/barriers -------
// Wave-global id g = blk*12 + w; bh = g/10, q-tile = g%10. K,Q direct; V packed (vp).
__global__ __launch_bounds__(768) void k_attn8(const unsigned short* __restrict__ qkv,
                                               const unsigned short* __restrict__ vp,
                                               unsigned short* __restrict__ y) {
    int g = blockIdx.x * 12 + (threadIdx.x >> 6);
    int qt = g % 10, bh = g / 10;
    int bt = bh / 12, h = bh % 12;
    const unsigned short* Qg = qkv + (size_t)bt * 320 * 2304 + h * 64;
    const unsigned short* Kg = Qg + 768;
    const unsigned short* Vpb = vp + (size_t)bh * 20480;   // 10 t * 4 frag * 512

    int l = threadIdx.x & 63;
    int q = l & 31, hh = l >> 5;
    int q0 = qt * 32;
    int ntile = (qt < 2) ? 2 : 10;

    bf16x8 qf[4];
#pragma unroll
    for (int c = 0; c < 4; ++c)
        qf[c] = *(const bf16x8*)(Qg + (size_t)(q0 + q) * 2304 + c * 16 + hh * 8);

    f32x16 o0 = (f32x16)0.f, o1 = (f32x16)0.f;
    float m = -3e38f, lsum = 0.f;
    const float SC = 0.125f * 1.44269504089f;

    for (int t = 0; t < ntile; ++t) {
        bf16x8 kf[4];
#pragma unroll
        for (int c = 0; c < 4; ++c)
            kf[c] = *(const bf16x8*)(Kg + (size_t)(t * 32 + q) * 2304 + c * 16 + hh * 8);
        bf16x8 v00 = *(const bf16x8*)(Vpb + (t * 4 + 0) * 512 + l * 8);
        bf16x8 v01 = *(const bf16x8*)(Vpb + (t * 4 + 1) * 512 + l * 8);
        bf16x8 v10 = *(const bf16x8*)(Vpb + (t * 4 + 2) * 512 + l * 8);
        bf16x8 v11 = *(const bf16x8*)(Vpb + (t * 4 + 3) * 512 + l * 8);

        f32x16 sacc = (f32x16)0.f;
#pragma unroll
        for (int c = 0; c < 4; ++c)
            sacc = __builtin_amdgcn_mfma_f32_32x32x16_bf16(kf[c], qf[c], sacc, 0, 0, 0);

        float p[16];
#pragma unroll
        for (int r = 0; r < 16; ++r) p[r] = sacc[r] * SC;
        float tm = fmaxf(
            fmaxf(fmaxf(fmaxf(p[0], p[1]), fmaxf(p[2], p[3])),
                  fmaxf(fmaxf(p[4], p[5]), fmaxf(p[6], p[7]))),
            fmaxf(fmaxf(fmaxf(p[8], p[9]), fmaxf(p[10], p[11])),
                  fmaxf(fmaxf(p[12], p[13]), fmaxf(p[14], p[15]))));
        tm = fmaxf(tm, __shfl_xor(tm, 32));
        if (!__all(tm <= m + 8.f)) {
            float mn = fmaxf(m, tm);
            float al = __builtin_amdgcn_exp2f(m - mn);
            lsum *= al;
#pragma unroll
            for (int r = 0; r < 16; ++r) { o0[r] *= al; o1[r] *= al; }
            m = mn;
        }
#pragma unroll
        for (int r = 0; r < 16; ++r) p[r] = __builtin_amdgcn_exp2f(p[r] - m);
        float rs =
            ((p[0] + p[1]) + (p[2] + p[3])) + ((p[4] + p[5]) + (p[6] + p[7])) +
            (((p[8] + p[9]) + (p[10] + p[11])) + ((p[12] + p[13]) + (p[14] + p[15])));
        lsum += rs;

        unsigned a0 = cvt_pk_bf16(p[0], p[1]);
        unsigned a1 = cvt_pk_bf16(p[2], p[3]);
        unsigned b0 = cvt_pk_bf16(p[4], p[5]);
        unsigned b1 = cvt_pk_bf16(p[6], p[7]);
        asm("v_permlane32_swap_b32 %0, %1" : "+v"(a0), "+v"(b0));
        asm("v_permlane32_swap_b32 %0, %1" : "+v"(a1), "+v"(b1));
        unsigned c0 = cvt_pk_bf16(p[8], p[9]);
        unsigned c1 = cvt_pk_bf16(p[10], p[11]);
        unsigned d0 = cvt_pk_bf16(p[12], p[13]);
        unsigned d1 = cvt_pk_bf16(p[14], p[15]);
        asm("v_permlane32_swap_b32 %0, %1" : "+v"(c0), "+v"(d0));
        asm("v_permlane32_swap_b32 %0, %1" : "+v"(c1), "+v"(d1));
        union { unsigned u[4]; bf16x8 v; } pf0, pf1;
        pf0.u[0] = a0; pf0.u[1] = a1; pf0.u[2] = b0; pf0.u[3] = b1;
        pf1.u[0] = c0; pf1.u[1] = c1; pf1.u[2] = d0; pf1.u[3] = d1;

        o0 = __builtin_amdgcn_mfma_f32_32x32x16_bf16(v00, pf0.v, o0, 0, 0, 0);
        o0 = __builtin_amdgcn_mfma_f32_32x32x16_bf16(v01, pf1.v, o0, 0, 0, 0);
        o1 = __builtin_amdgcn_mfma_f32_32x32x16_bf16(v10, pf0.v, o1, 0, 0, 0);
        o1 = __builtin_amdgcn_mfma_f32_32x32x16_bf16(v11, pf1.v, o1, 0, 0, 0);
    }

    lsum += __shfl_xor(lsum, 32);
    float inv = 1.f / lsum;
    unsigned short* yp = y + (size_t)(bt * 320 + q0 + q) * 768 + h * 64;
#pragma unroll
    for (int r = 0; r < 16; r += 2) {
        int dr = (r & 3) + 8 * (r >> 2) + 4 * hh;
        *(unsigned*)(yp + dr) =
            (unsigned)f2bf(o0[r] * inv) | ((unsigned)f2bf(o0[r + 1] * inv) << 16);
        *(unsigned*)(yp + 32 + dr) =
            (unsigned)f2bf(o1[r] * inv) | ((unsigned)f2bf(o1[r + 1] * inv) << 16);
    }
}

// ---------------- launcher ----------------
extern "C" void kernel_launch(void* const* d_in, const int* in_sizes, int n_in,
                              void* d_out, int out_size, void* d_ws, size_t ws_size,
                              hipStream_t stream) {
    const float* x     = (const float*)d_in[0];
    const float* qkv_w = (const float*)d_in[1];
    const float* qkv_b = (const float*)d_in[2];
    const float* out_w = (const float*)d_in[3];
    const float* out_b = (const float*)d_in[4];

    const int M = 40960;  // B*T*S = 4*32*320
    unsigned short* xb  = (unsigned short*)d_ws;
    unsigned short* w1t = xb + (size_t)M * 768;           // [2304][768]
    unsigned short* w2t = w1t + (size_t)2304 * 768;       // [768][768]
    unsigned short* qkv = w2t + (size_t)768 * 768;        // [M][2304]
    unsigned short* yb  = qkv + (size_t)M * 2304;         // [M][768]
    unsigned short* vp  = xb;                             // aliases xb (dead after gemm1)

    k_convert<<<(M * 768 / 8 + 255) / 256, 256, 0, stream>>>(x, xb, M * 768 / 8);
    k_transpose<<<dim3(2304 / 32, 768 / 32), dim3(32, 8), 0, stream>>>(qkv_w, w1t, 768, 2304);
    k_transpose<<<dim3(768 / 32, 768 / 32), dim3(32, 8), 0, stream>>>(out_w, w2t, 768, 768);

    k_gemm256<true><<<(M / 256) * (2304 / 256), 512, 0, stream>>>(xb, w1t, qkv_b, (void*)qkv, M, 2304, 768);
    k_vpack<<<1536 * 10, 256, 0, stream>>>(qkv, vp);
    k_attn8<<<1280, 768, 0, stream>>>(qkv, vp, yb);
    k_gemm256<false><<<(M / 256) * (768 / 256), 512, 0, stream>>>(yb, w2t, out_b, d_out, M, 768, 768);
}

// Round 15
// 379.263 us; speedup vs baseline: 1.1999x; 1.0811x over previous
//
#include <hip/hip_runtime.h>

typedef __attribute__((ext_vector_type(8))) short bf16x8;
typedef __attribute__((ext_vector_type(4))) float f32x4;
typedef __attribute__((ext_vector_type(16))) float f32x16;
typedef __attribute__((address_space(1))) void gvoid_t;
typedef __attribute__((address_space(3))) void lvoid_t;

#define DEVI __device__ __forceinline__
#define SB __builtin_amdgcn_sched_barrier(0)

DEVI unsigned short f2bf(float f) {
    unsigned int u = __builtin_bit_cast(unsigned int, f);
    u += 0x7fffu + ((u >> 16) & 1u);   // RNE
    return (unsigned short)(u >> 16);
}

DEVI unsigned cvt_pk_bf16(float a, float b) {
    unsigned r;
    asm("v_cvt_pk_bf16_f32 %0, %1, %2" : "=v"(r) : "v"(a), "v"(b));
    return r;
}

DEVI f32x4 mfma16(bf16x8 a, bf16x8 b, f32x4 c) {
    return __builtin_amdgcn_mfma_f32_16x16x32_bf16(a, b, c, 0, 0, 0);
}

// ---------------- fp32 -> bf16 elementwise (8 elems/thread) ----------------
__global__ void k_convert(const float* __restrict__ in, unsigned short* __restrict__ out, int n8) {
    int i = blockIdx.x * 256 + threadIdx.x;
    if (i >= n8) return;
    const float4* p = (const float4*)in + (size_t)i * 2;
    float4 a = p[0], b = p[1];
    uint4 o;
    o.x = f2bf(a.x) | ((unsigned)f2bf(a.y) << 16);
    o.y = f2bf(a.z) | ((unsigned)f2bf(a.w) << 16);
    o.z = f2bf(b.x) | ((unsigned)f2bf(b.y) << 16);
    o.w = f2bf(b.z) | ((unsigned)f2bf(b.w) << 16);
    *((uint4*)out + i) = o;
}

// ---------------- transpose+convert: w[K][N] f32 -> wt[N][K] bf16 ----------------
__global__ void k_transpose(const float* __restrict__ w, unsigned short* __restrict__ wt, int K, int N) {
    __shared__ float tile[32][33];
    int n0 = blockIdx.x * 32, k0 = blockIdx.y * 32;
    int tx = threadIdx.x, ty = threadIdx.y;
#pragma unroll
    for (int r = 0; r < 32; r += 8)
        tile[ty + r][tx] = w[(size_t)(k0 + ty + r) * N + n0 + tx];
    __syncthreads();
#pragma unroll
    for (int r = 0; r < 32; r += 8)
        wt[(size_t)(n0 + ty + r) * K + k0 + tx] = f2bf(tile[tx][ty + r]);
}

// ---------------- K fragment-pack ----------------
__global__ __launch_bounds__(256) void k_kpack(const unsigned short* __restrict__ qkv,
                                               unsigned short* __restrict__ kp) {
    int bht = blockIdx.x;            // (bt*12+h)*10 + t
    int t = bht % 10, bh = bht / 10;
    int h = bh % 12, bt = bh / 12;
    int c = threadIdx.x >> 6, l = threadIdx.x & 63;
    const unsigned short* src = qkv + (size_t)(bt * 320 + t * 32 + (l & 31)) * 2304
                                + 768 + h * 64 + c * 16 + (l >> 5) * 8;
    uint4 v = *(const uint4*)src;
    *(uint4*)(kp + ((size_t)bht * 4 + c) * 512 + l * 8) = v;
}

// ---------------- 256x256 free-run bf16 GEMM: all t+1 stages in P0 ------------------
template <bool OUT_BF16>
__global__ __launch_bounds__(512, 2) void k_gemm256(const unsigned short* __restrict__ A,
                                                    const unsigned short* __restrict__ Bt,
                                                    const float* __restrict__ bias,
                                                    void* __restrict__ out,
                                                    int M, int N, int K) {
    __shared__ unsigned short smem[65536];   // A[2][256][64] @0, B[2][256][64] @32768

    const int tid = threadIdx.x;
    const int nwg = gridDim.x, bid = blockIdx.x;
    const int q8 = nwg >> 3, r8 = nwg & 7;
    const int xcd = bid & 7, lid = bid >> 3;
    const int swz = ((xcd < r8) ? xcd * (q8 + 1) : r8 * (q8 + 1) + (xcd - r8) * q8) + lid;
    const int ntn = N >> 8;
    const int bm = swz / ntn, bn = swz % ntn;

    const int lane = tid & 63, wid = tid >> 6;
    const int wr = wid >> 2, wc = wid & 3;
    const int lr = lane & 15, lg = lane >> 4;
    const int cswz = (lr & 7) << 3;
    const int col0 = (lg * 8) ^ cswz;

    const int NT = K >> 6;

    const int srowl = tid >> 3;
    const int scole = ((tid & 7) ^ (srowl & 7)) << 3;
    const unsigned short* aSrc = A  + (size_t)(bm * 256 + srowl) * K + scole;
    const unsigned short* bSrc = Bt + (size_t)(bn * 256 + srowl) * K + scole;

#define STG(matOff, srcBase, qq, koff, bufw)                                              \
    __builtin_amdgcn_global_load_lds((gvoid_t*)((srcBase) + (size_t)(qq) * 64 * K + (koff)), \
        (lvoid_t*)(smem + (matOff) + (bufw) * 16384 + (qq) * 4096 + tid * 8), 16, 0, 0)
#define LDA(mf, base, rowoff, kk) \
    *(const bf16x8*)((base) + ((rowoff) + (mf) * 16 + lr) * 64 + (col0 ^ ((kk) * 32)))

    f32x4 acc[8][4];
#pragma unroll
    for (int i = 0; i < 8; ++i)
#pragma unroll
        for (int j = 0; j < 4; ++j) acc[i][j] = (f32x4){0.f, 0.f, 0.f, 0.f};

    {   // prologue: tile0 fully + tile1 A0,A2
        const int k1 = (NT > 1) ? 64 : 0;
        STG(0, aSrc, 0, 0, 0); STG(0, aSrc, 1, 0, 0); STG(0, aSrc, 2, 0, 0); STG(0, aSrc, 3, 0, 0);
        STG(32768, bSrc, 0, 0, 0); STG(32768, bSrc, 1, 0, 0); STG(32768, bSrc, 2, 0, 0); STG(32768, bSrc, 3, 0, 0);
        STG(0, aSrc, 0, k1, 1); STG(0, aSrc, 2, k1, 1);
        asm volatile("s_waitcnt vmcnt(2)" ::: "memory");
        __builtin_amdgcn_s_barrier();
    }

#pragma unroll 1
    for (int t = 0; t < NT; ++t) {
        const int bufR = t & 1, bufW = bufR ^ 1;
        const int ko1 = (t + 1 < NT) ? (t + 1) * 64 : 0;
        const int ko2 = (t + 2 < NT) ? (t + 2) * 64 : 0;
        const unsigned short* abuf = smem + bufR * 16384;
        const unsigned short* bbuf = smem + 32768 + bufR * 16384;
        bf16x8 afv[4][2], b01[2][2], b23[2][2];

        // ===== P0: (mh=0) x (nh=0); issue ALL 6 t+1 stages here =====
#pragma unroll
        for (int j = 0; j < 2; ++j)
#pragma unroll
            for (int kk = 0; kk < 2; ++kk)
                b01[j][kk] = LDA(j, bbuf, wc * 64, kk);
#pragma unroll
        for (int mf = 0; mf < 2; ++mf)
#pragma unroll
            for (int kk = 0; kk < 2; ++kk)
                afv[mf][kk] = LDA(mf, abuf, wr * 128, kk);
        SB;
#pragma unroll
        for (int mf = 2; mf < 4; ++mf)
#pragma unroll
            for (int kk = 0; kk < 2; ++kk)
                afv[mf][kk] = LDA(mf, abuf, wr * 128, kk);
        SB;
        STG(32768, bSrc, 0, ko1, bufW); STG(32768, bSrc, 1, ko1, bufW);
        STG(32768, bSrc, 2, ko1, bufW); STG(32768, bSrc, 3, ko1, bufW);
        STG(0, aSrc, 1, ko1, bufW); STG(0, aSrc, 3, ko1, bufW);
        asm volatile("s_waitcnt lgkmcnt(4)" ::: "memory"); SB;
        __builtin_amdgcn_s_setprio(1);
#pragma unroll
        for (int mf = 0; mf < 2; ++mf)
#pragma unroll
            for (int j = 0; j < 2; ++j)
#pragma unroll
                for (int kk = 0; kk < 2; ++kk)
                    acc[mf][j] = mfma16(afv[mf][kk], b01[j][kk], acc[mf][j]);
        __builtin_amdgcn_s_setprio(0);
        asm volatile("s_waitcnt lgkmcnt(0)" ::: "memory"); SB;
        __builtin_amdgcn_s_setprio(1);
#pragma unroll
        for (int mf = 2; mf < 4; ++mf)
#pragma unroll
            for (int j = 0; j < 2; ++j)
#pragma unroll
                for (int kk = 0; kk < 2; ++kk)
                    acc[mf][j] = mfma16(afv[mf][kk], b01[j][kk], acc[mf][j]);
        __builtin_amdgcn_s_setprio(0);

        // ===== P1: (mh=0) x (nh=1) =====
#pragma unroll
        for (int kk = 0; kk < 2; ++kk)
            b23[0][kk] = LDA(2, bbuf, wc * 64, kk);
        SB;
#pragma unroll
        for (int kk = 0; kk < 2; ++kk)
            b23[1][kk] = LDA(3, bbuf, wc * 64, kk);
        SB;
        asm volatile("s_waitcnt lgkmcnt(2)" ::: "memory"); SB;
        __builtin_amdgcn_s_setprio(1);
#pragma unroll
        for (int mf = 0; mf < 4; ++mf)
#pragma unroll
            for (int kk = 0; kk < 2; ++kk)
                acc[mf][2] = mfma16(afv[mf][kk], b23[0][kk], acc[mf][2]);
        __builtin_amdgcn_s_setprio(0);
        asm volatile("s_waitcnt lgkmcnt(0)" ::: "memory"); SB;
        __builtin_amdgcn_s_setprio(1);
#pragma unroll
        for (int mf = 0; mf < 4; ++mf)
#pragma unroll
            for (int kk = 0; kk < 2; ++kk)
                acc[mf][3] = mfma16(afv[mf][kk], b23[1][kk], acc[mf][3]);
        __builtin_amdgcn_s_setprio(0);

        // ===== P2: (mh=1) x (nh=1) =====
#pragma unroll
        for (int mf = 0; mf < 2; ++mf)
#pragma unroll
            for (int kk = 0; kk < 2; ++kk)
                afv[mf][kk] = LDA(mf, abuf, wr * 128 + 64, kk);
        SB;
#pragma unroll
        for (int mf = 2; mf < 4; ++mf)
#pragma unroll
            for (int kk = 0; kk < 2; ++kk)
                afv[mf][kk] = LDA(mf, abuf, wr * 128 + 64, kk);
        SB;
        asm volatile("s_waitcnt lgkmcnt(4)" ::: "memory"); SB;
        __builtin_amdgcn_s_setprio(1);
#pragma unroll
        for (int mf = 0; mf < 2; ++mf)
#pragma unroll
            for (int j = 0; j < 2; ++j)
#pragma unroll
                for (int kk = 0; kk < 2; ++kk)
                    acc[4 + mf][2 + j] = mfma16(afv[mf][kk], b23[j][kk], acc[4 + mf][2 + j]);
        __builtin_amdgcn_s_setprio(0);
        asm volatile("s_waitcnt lgkmcnt(0)" ::: "memory"); SB;
        __builtin_amdgcn_s_setprio(1);
#pragma unroll
        for (int mf = 2; mf < 4; ++mf)
#pragma unroll
            for (int j = 0; j < 2; ++j)
#pragma unroll
                for (int kk = 0; kk < 2; ++kk)
                    acc[4 + mf][2 + j] = mfma16(afv[mf][kk], b23[j][kk], acc[4 + mf][2 + j]);
        __builtin_amdgcn_s_setprio(0);

        // ===== P3: (mh=1) x (nh=0) — regs only =====
        __builtin_amdgcn_s_setprio(1);
#pragma unroll
        for (int mf = 0; mf < 4; ++mf)
#pragma unroll
            for (int j = 0; j < 2; ++j)
#pragma unroll
                for (int kk = 0; kk < 2; ++kk)
                    acc[4 + mf][j] = mfma16(afv[mf][kk], b01[j][kk], acc[4 + mf][j]);
        __builtin_amdgcn_s_setprio(0);
        // tile boundary: all t+1 stages had ~3.5 phases to land -> vmcnt(0) ~free
        asm volatile("s_waitcnt vmcnt(0)" ::: "memory");
        __builtin_amdgcn_s_barrier();
        STG(0, aSrc, 0, ko2, bufR); STG(0, aSrc, 2, ko2, bufR);
    }
#undef STG
#undef LDA

    // ---- epilogue: drain stray prefetches, block-sync, then LDS-staged stores ----
    asm volatile("s_waitcnt vmcnt(0)" ::: "memory");
    __syncthreads();
    float bv[4];
#pragma unroll
    for (int nf = 0; nf < 4; ++nf)
        bv[nf] = bias[bn * 256 + wc * 64 + nf * 16 + lr];

    if (OUT_BF16) {
        unsigned short* ebuf = smem + wid * 8192;
#pragma unroll
        for (int h = 0; h < 2; ++h) {
#pragma unroll
            for (int mf4 = 0; mf4 < 4; ++mf4) {
                int mf = h * 4 + mf4;
#pragma unroll
                for (int nf = 0; nf < 4; ++nf)
#pragma unroll
                    for (int i = 0; i < 4; ++i)
                        ebuf[(mf4 * 16 + lg * 4 + i) * 72 + nf * 16 + lr] = f2bf(acc[mf][nf][i] + bv[nf]);
            }
            asm volatile("s_waitcnt lgkmcnt(0)" ::: "memory"); SB;
#pragma unroll
            for (int ps = 0; ps < 8; ++ps) {
                int rl = ps * 8 + (lane >> 3), ck = lane & 7;
                uint4 vv = *(const uint4*)&ebuf[rl * 72 + ck * 8];
                int grow = bm * 256 + wr * 128 + h * 64 + rl;
                int gcol = bn * 256 + wc * 64 + ck * 8;
                *(uint4*)&((unsigned short*)out)[(size_t)grow * N + gcol] = vv;
            }
            asm volatile("s_waitcnt lgkmcnt(0)" ::: "memory"); SB;
        }
    } else {
        float* ebuf = (float*)smem + wid * 4096;
#pragma unroll
        for (int qq = 0; qq < 4; ++qq) {
#pragma unroll
            for (int m2 = 0; m2 < 2; ++m2) {
                int mf = qq * 2 + m2;
#pragma unroll
                for (int nf = 0; nf < 4; ++nf)
#pragma unroll
                    for (int i = 0; i < 4; ++i)
                        ebuf[(m2 * 16 + lg * 4 + i) * 68 + nf * 16 + lr] = acc[mf][nf][i] + bv[nf];
            }
            asm volatile("s_waitcnt lgkmcnt(0)" ::: "memory"); SB;
#pragma unroll
            for (int ps = 0; ps < 8; ++ps) {
                int rl = ps * 4 + (lane >> 4), ck = lane & 15;
                uint4 vv = *(const uint4*)&ebuf[rl * 68 + ck * 4];
                int grow = bm * 256 + wr * 128 + qq * 32 + rl;
                int gcol = bn * 256 + wc * 64 + ck * 4;
                *(uint4*)&((float*)out)[(size_t)grow * N + gcol] = vv;
            }
            asm volatile("s_waitcnt lgkmcnt(0)" ::: "memory"); SB;
        }
    }
}

// ---------------- fused flash attention v5: full-V LDS + packed-K coalesced loads ----
__global__ __launch_bounds__(640) void k_attn5(const unsigned short* __restrict__ qkv,
                                               const unsigned short* __restrict__ kp,
                                               unsigned short* __restrict__ y) {
    int bt = blockIdx.x / 12, h = blockIdx.x % 12;
    const unsigned short* Qg = qkv + (size_t)bt * 320 * 2304 + h * 64;
    const unsigned short* Vg = Qg + 1536;
    const unsigned short* Kpb = kp + (size_t)blockIdx.x * 20480;   // 10 tiles * 4c * 512

    __shared__ unsigned short Vt[10 * 64 * 40];   // [t][d][k'], swizzled per-tile

    int tid = threadIdx.x, w = tid >> 6, l = tid & 63;
    int q = l & 31, hh = l >> 5;
    int q0 = w * 32;
    int ntile = (w < 2) ? 2 : 10;

    {   // one-time V staging: thread -> V row k = tid>>1, d-half (tid&1)*32
        int k = tid >> 1;
        int tt = k >> 5, sk = k & 31;
        int d0 = (tid & 1) * 32;
        const unsigned short* src = Vg + (size_t)k * 2304 + d0;
#pragma unroll
        for (int c = 0; c < 4; ++c) {
            union { uint4 u; unsigned short s[8]; } vv;
            vv.u = *(const uint4*)(src + c * 8);
#pragma unroll
            for (int j = 0; j < 8; ++j) {
                int d = d0 + c * 8 + j;
                Vt[(tt * 64 + d) * 40 + (sk ^ (((d >> 3) & 3) << 3))] = vv.s[j];
            }
        }
    }

    bf16x8 qf[4];
#pragma unroll
    for (int c = 0; c < 4; ++c)
        qf[c] = *(const bf16x8*)(Qg + (size_t)(q0 + q) * 2304 + c * 16 + hh * 8);

    f32x16 o0 = (f32x16)0.f, o1 = (f32x16)0.f;
    float m = -3e38f, lsum = 0.f;
    const float SC = 0.125f * 1.44269504089f;

    bf16x8 kfA[4], kfB[4];
    auto loadK = [&](bf16x8 (&kf)[4], int tt) {
#pragma unroll
        for (int c = 0; c < 4; ++c)
            kf[c] = *(const bf16x8*)(Kpb + tt * 2048 + c * 512 + l * 8);
    };
    loadK(kfA, 0);

    __syncthreads();   // Vt ready; no further block syncs

    auto process = [&](int t, bf16x8 (&kf)[4]) {
        f32x16 sacc = (f32x16)0.f;
#pragma unroll
        for (int c = 0; c < 4; ++c)
            sacc = __builtin_amdgcn_mfma_f32_32x32x16_bf16(kf[c], qf[c], sacc, 0, 0, 0);

        float p[16];
#pragma unroll
        for (int r = 0; r < 16; ++r) p[r] = sacc[r] * SC;
        float tm = fmaxf(
            fmaxf(fmaxf(fmaxf(p[0], p[1]), fmaxf(p[2], p[3])),
                  fmaxf(fmaxf(p[4], p[5]), fmaxf(p[6], p[7]))),
            fmaxf(fmaxf(fmaxf(p[8], p[9]), fmaxf(p[10], p[11])),
                  fmaxf(fmaxf(p[12], p[13]), fmaxf(p[14], p[15]))));
        tm = fmaxf(tm, __shfl_xor(tm, 32));
        if (!__all(tm <= m + 8.f)) {
            float mn = fmaxf(m, tm);
            float al = __builtin_amdgcn_exp2f(m - mn);
            lsum *= al;
#pragma unroll
            for (int r = 0; r < 16; ++r) { o0[r] *= al; o1[r] *= al; }
            m = mn;
        }
#pragma unroll
        for (int r = 0; r < 16; ++r) p[r] = __builtin_amdgcn_exp2f(p[r] - m);
        float rs =
            ((p[0] + p[1]) + (p[2] + p[3])) + ((p[4] + p[5]) + (p[6] + p[7])) +
            (((p[8] + p[9]) + (p[10] + p[11])) + ((p[12] + p[13]) + (p[14] + p[15])));
        lsum += rs;

        unsigned a0 = cvt_pk_bf16(p[0], p[1]);
        unsigned a1 = cvt_pk_bf16(p[2], p[3]);
        unsigned b0 = cvt_pk_bf16(p[4], p[5]);
        unsigned b1 = cvt_pk_bf16(p[6], p[7]);
        asm("v_permlane32_swap_b32 %0, %1" : "+v"(a0), "+v"(b0));
        asm("v_permlane32_swap_b32 %0, %1" : "+v"(a1), "+v"(b1));
        unsigned c0 = cvt_pk_bf16(p[8], p[9]);
        unsigned c1 = cvt_pk_bf16(p[10], p[11]);
        unsigned d0 = cvt_pk_bf16(p[12], p[13]);
        unsigned d1 = cvt_pk_bf16(p[14], p[15]);
        asm("v_permlane32_swap_b32 %0, %1" : "+v"(c0), "+v"(d0));
        asm("v_permlane32_swap_b32 %0, %1" : "+v"(c1), "+v"(d1));
        union { unsigned u[4]; bf16x8 v; } pf0, pf1;
        pf0.u[0] = a0; pf0.u[1] = a1; pf0.u[2] = b0; pf0.u[3] = b1;
        pf1.u[0] = c0; pf1.u[1] = c1; pf1.u[2] = d0; pf1.u[3] = d1;

        const unsigned short* vt = Vt + t * 2560;
        {
            int d = q;
            int sw = (d >> 3) & 3;
            bf16x8 va0 = *(const bf16x8*)&vt[d * 40 + ((0 + hh) ^ sw) * 8];
            bf16x8 va1 = *(const bf16x8*)&vt[d * 40 + ((2 + hh) ^ sw) * 8];
            o0 = __builtin_amdgcn_mfma_f32_32x32x16_bf16(va0, pf0.v, o0, 0, 0, 0);
            o0 = __builtin_amdgcn_mfma_f32_32x32x16_bf16(va1, pf1.v, o0, 0, 0, 0);
        }
        {
            int d = 32 + q;
            int sw = (d >> 3) & 3;
            bf16x8 va0 = *(const bf16x8*)&vt[d * 40 + ((0 + hh) ^ sw) * 8];
            bf16x8 va1 = *(const bf16x8*)&vt[d * 40 + ((2 + hh) ^ sw) * 8];
            o1 = __builtin_amdgcn_mfma_f32_32x32x16_bf16(va0, pf0.v, o1, 0, 0, 0);
            o1 = __builtin_amdgcn_mfma_f32_32x32x16_bf16(va1, pf1.v, o1, 0, 0, 0);
        }
    };

    for (int t = 0; t < ntile; t += 2) {
        loadK(kfB, t + 1);
        process(t, kfA);
        loadK(kfA, (t + 2 < 10) ? (t + 2) : 8);
        process(t + 1, kfB);
    }

    lsum += __shfl_xor(lsum, 32);
    float inv = 1.f / lsum;
    unsigned short* yp = y + (size_t)(bt * 320 + q0 + q) * 768 + h * 64;
#pragma unroll
    for (int r = 0; r < 16; r += 2) {
        int dr = (r & 3) + 8 * (r >> 2) + 4 * hh;
        *(unsigned*)(yp + dr) =
            (unsigned)f2bf(o0[r] * inv) | ((unsigned)f2bf(o0[r + 1] * inv) << 16);
        *(unsigned*)(yp + 32 + dr) =
            (unsigned)f2bf(o1[r] * inv) | ((unsigned)f2bf(o1[r + 1] * inv) << 16);
    }
}

// ---------------- launcher ----------------
extern "C" void kernel_launch(void* const* d_in, const int* in_sizes, int n_in,
                              void* d_out, int out_size, void* d_ws, size_t ws_size,
                              hipStream_t stream) {
    const float* x     = (const float*)d_in[0];
    const float* qkv_w = (const float*)d_in[1];
    const float* qkv_b = (const float*)d_in[2];
    const float* out_w = (const float*)d_in[3];
    const float* out_b = (const float*)d_in[4];

    const int M = 40960;  // B*T*S = 4*32*320
    unsigned short* xb  = (unsigned short*)d_ws;
    unsigned short* w1t = xb + (size_t)M * 768;           // [2304][768]
    unsigned short* w2t = w1t + (size_t)2304 * 768;       // [768][768]
    unsigned short* qkv = w2t + (size_t)768 * 768;        // [M][2304]
    unsigned short* yb  = qkv + (size_t)M * 2304;         // [M][768]
    unsigned short* kp  = xb;                             // aliases xb (dead after gemm1)

    k_convert<<<(M * 768 / 8 + 255) / 256, 256, 0, stream>>>(x, xb, M * 768 / 8);
    k_transpose<<<dim3(2304 / 32, 768 / 32), dim3(32, 8), 0, stream>>>(qkv_w, w1t, 768, 2304);
    k_transpose<<<dim3(768 / 32, 768 / 32), dim3(32, 8), 0, stream>>>(out_w, w2t, 768, 768);

    k_gemm256<true><<<(M / 256) * (2304 / 256), 512, 0, stream>>>(xb, w1t, qkv_b, (void*)qkv, M, 2304, 768);
    k_kpack<<<1536 * 10, 256, 0, stream>>>(qkv, kp);
    k_attn5<<<128 * 12, 640, 0, stream>>>(qkv, kp, yb);
    k_gemm256<false><<<(M / 256) * (768 / 256), 512, 0, stream>>>(yb, w2t, out_b, d_out, M, 768, 768);
}